// Round 13
// baseline (6348.973 us; speedup 1.0000x reference)
//
#include <hip/hip_runtime.h>
#include <hip/hip_fp16.h>

typedef _Float16 f16;
typedef _Float16 f16x8 __attribute__((ext_vector_type(8)));
typedef _Float16 f16x4 __attribute__((ext_vector_type(4)));
typedef float f32x4 __attribute__((ext_vector_type(4)));

#define B_ 128
#define T_ 512
#define NBLK 256

// ---------------- workspace layout (bytes) ----------------
static constexpr size_t OFF_BAR   = 0;                         // 8 groups x 32 slots x 16B = 4KB
static constexpr size_t OFF_LEN   = 4096;                      // 128 int
static constexpr size_t OFF_BIAS0 = 8192;                      // 2048 f32
static constexpr size_t OFF_BIAS1 = 16384;                     // 2048 f32
static constexpr size_t OFF_W0    = 32768;                     // 2048x1024 f16, rows u*4+g, [w_ih|w_hh]
static constexpr size_t OFF_W1    = OFF_W0 + 4u*1024u*1024u;
static constexpr size_t OFF_H0    = OFF_W1 + 4u*1024u*1024u;   // 4 bufs x 128x512 f16
static constexpr size_t OFF_H1    = OFF_H0 + 4u*131072u;       // 2 bufs x 128x512 f16
static constexpr size_t OFF_H1F   = OFF_H1 + 2u*131072u;       // 128x512 f32
static constexpr size_t WS_BASE   = OFF_H1F + 262144;
static constexpr size_t OFF_X0    = WS_BASE;                   // f16 [T][B][2048]
static constexpr size_t X0_SZ     = (size_t)T_ * 128 * 2048 * 2;
static constexpr size_t WS_PRE    = OFF_X0 + X0_SZ;

// ---- batched mall-coherent load blob (issue -> IMMEDIATE waitvm0; never defer) ----
__device__ __forceinline__ void ldblob16(const void* p, f16x8* v) {
    asm volatile(
        "global_load_dwordx4 %0, %16, off offset:0 sc0 sc1\n\t"
        "global_load_dwordx4 %1, %16, off offset:64 sc0 sc1\n\t"
        "global_load_dwordx4 %2, %16, off offset:128 sc0 sc1\n\t"
        "global_load_dwordx4 %3, %16, off offset:192 sc0 sc1\n\t"
        "global_load_dwordx4 %4, %16, off offset:256 sc0 sc1\n\t"
        "global_load_dwordx4 %5, %16, off offset:320 sc0 sc1\n\t"
        "global_load_dwordx4 %6, %16, off offset:384 sc0 sc1\n\t"
        "global_load_dwordx4 %7, %16, off offset:448 sc0 sc1\n\t"
        "global_load_dwordx4 %8, %16, off offset:512 sc0 sc1\n\t"
        "global_load_dwordx4 %9, %16, off offset:576 sc0 sc1\n\t"
        "global_load_dwordx4 %10, %16, off offset:640 sc0 sc1\n\t"
        "global_load_dwordx4 %11, %16, off offset:704 sc0 sc1\n\t"
        "global_load_dwordx4 %12, %16, off offset:768 sc0 sc1\n\t"
        "global_load_dwordx4 %13, %16, off offset:832 sc0 sc1\n\t"
        "global_load_dwordx4 %14, %16, off offset:896 sc0 sc1\n\t"
        "global_load_dwordx4 %15, %16, off offset:960 sc0 sc1"
        : "=&v"(v[0]), "=&v"(v[1]), "=&v"(v[2]), "=&v"(v[3]),
          "=&v"(v[4]), "=&v"(v[5]), "=&v"(v[6]), "=&v"(v[7]),
          "=&v"(v[8]), "=&v"(v[9]), "=&v"(v[10]), "=&v"(v[11]),
          "=&v"(v[12]), "=&v"(v[13]), "=&v"(v[14]), "=&v"(v[15])
        : "v"(p) : "memory");
}
__device__ __forceinline__ void waitvm0() {
    asm volatile("s_waitcnt vmcnt(0)" ::: "memory");
    __builtin_amdgcn_sched_barrier(0);
}
__device__ __forceinline__ void stwt16(void* p, f16x8 v) {
    asm volatile("global_store_dwordx4 %0, %1, off sc0 sc1" :: "v"(p), "v"(v) : "memory");
}
__device__ __forceinline__ void sbar_lgkm0() {
    asm volatile("s_waitcnt lgkmcnt(0)\n\ts_barrier" ::: "memory");
}

// ---------------- lengths ----------------
__global__ __launch_bounds__(512) void k_len(const float* __restrict__ x, int* __restrict__ len) {
    int b = blockIdx.x, q = blockIdx.y;
    int rl = threadIdx.x >> 2, part = threadIdx.x & 3;
    const float4* p = (const float4*)(x + ((size_t)b * T_ + q * 128 + rl) * 512 + part * 128);
    float s = 0.f;
    #pragma unroll
    for (int i = 0; i < 32; ++i) { float4 v = p[i]; s += v.x + v.y + v.z + v.w; }
    s += __shfl_xor(s, 1);
    s += __shfl_xor(s, 2);
    int cnt = __syncthreads_count(part == 0 && s != 0.0f);
    if (threadIdx.x == 0) atomicAdd(&len[b], cnt);
}

// ---------------- weight convert: rows u*4+gate, [w_ih|w_hh], f32->f16 ----------------
__global__ __launch_bounds__(256) void k_wcvt(const float* __restrict__ wih, const float* __restrict__ whh,
                                              const float* __restrict__ bih, const float* __restrict__ bhh,
                                              f16* __restrict__ W, float* __restrict__ bias) {
    int r = blockIdx.x;
    int h = r >> 2, g = r & 3;
    int src = g * 512 + h;
    const float* a = wih + (size_t)src * 512;
    const float* bsrc = whh + (size_t)src * 512;
    f16* dst = W + (size_t)r * 1024;
    #pragma unroll
    for (int j = 0; j < 2; ++j) {
        int k = threadIdx.x + j * 256;
        dst[k]       = (f16)a[k];
        dst[k + 512] = (f16)bsrc[k];
    }
    if (threadIdx.x == 0) bias[r] = bih[src] + bhh[src];
}

// ---------------- X0 precompute, x-stationary ----------------
__global__ __launch_bounds__(256) void k_xgemm(const float* __restrict__ x, const f16* __restrict__ W0,
                                               const float* __restrict__ bias0, f16* __restrict__ X0) {
    extern __shared__ char lds[];          // 64K xtile + 64K wtile + 8K outstage
    char* xt = lds;
    char* wt = lds + 65536;
    char* ot = lds + 131072;
    const int b = blockIdx.x, tc = blockIdx.y;
    const int tid = threadIdx.x;
    const int tf = tid >> 6, lane = tid & 63;
    const int l16 = lane & 15, l4 = lane >> 4;

    {   // stage x tile: B-operand frag-major
        const int t = tid >> 2, q = tid & 3;
        const float* src = x + ((size_t)b * 512 + tc * 64 + t) * 512 + q * 128;
        #pragma unroll
        for (int j = 0; j < 16; ++j) {
            const float4 p0 = *(const float4*)(src + j * 8);
            const float4 p1 = *(const float4*)(src + j * 8 + 4);
            f16x8 v = { (f16)p0.x,(f16)p0.y,(f16)p0.z,(f16)p0.w,
                        (f16)p1.x,(f16)p1.y,(f16)p1.z,(f16)p1.w };
            const int k = q * 128 + j * 8;
            *(f16x8*)(xt + ((t >> 4) * 16 + (k >> 5)) * 1024
                         + ((t & 15) + ((k >> 3) & 3) * 16) * 16) = v;
        }
    }
    __syncthreads();

    for (int cg = 0; cg < 32; ++cg) {
        {   // stage W tile (ih half), A-operand frag-major
            const int r = tid >> 2, q = tid & 3;
            const f16* src = W0 + (size_t)(cg * 64 + r) * 1024 + q * 128;
            #pragma unroll
            for (int j = 0; j < 16; ++j) {
                f16x8 w = *(const f16x8*)(src + j * 8);
                const int k = q * 128 + j * 8;
                *(f16x8*)(wt + ((k >> 5) * 4 + (r >> 4)) * 1024
                             + ((r & 15) + ((k >> 3) & 3) * 16) * 16) = w;
            }
        }
        __syncthreads();
        f32x4 acc[4] = {};
        #pragma unroll
        for (int ks = 0; ks < 16; ++ks) {
            f16x8 bx = *(const f16x8*)(xt + (tf * 16 + ks) * 1024 + lane * 16);
            #pragma unroll
            for (int nf = 0; nf < 4; ++nf) {
                f16x8 aw = *(const f16x8*)(wt + (ks * 4 + nf) * 1024 + lane * 16);
                acc[nf] = __builtin_amdgcn_mfma_f32_16x16x32_f16(aw, bx, acc[nf], 0, 0, 0);
            }
        }
        {   // bias + pack to outstage (swizzled)
            const int t = tf * 16 + l16;
            const int sw = (t & 7) << 4;
            #pragma unroll
            for (int nf = 0; nf < 4; ++nf) {
                const float4 b4 = *(const float4*)(bias0 + cg * 64 + nf * 16 + l4 * 4);
                f16x4 v = { (f16)(acc[nf][0] + b4.x), (f16)(acc[nf][1] + b4.y),
                            (f16)(acc[nf][2] + b4.z), (f16)(acc[nf][3] + b4.w) };
                const int byte = t * 128 + nf * 32 + l4 * 8;
                *(f16x4*)(ot + (byte ^ sw)) = v;
            }
        }
        __syncthreads();
        {   // coalesced NT store
            const int t = tid >> 2, ch = tid & 3;
            const int sw = (t & 7) << 4;
            const int byte = t * 128 + ch * 32;
            f16x8 v0 = *(const f16x8*)(ot + (byte ^ sw));
            f16x8 v1 = *(const f16x8*)(ot + ((byte + 16) ^ sw));
            f16* dst = X0 + ((size_t)(tc * 64 + t) * 128 + b) * 2048 + cg * 64 + ch * 16;
            __builtin_nontemporal_store(v0, (f16x8*)dst);
            __builtin_nontemporal_store(v1, (f16x8*)(dst + 8));
        }
        __syncthreads();
    }
}

// ---------------- persistent kernel: 1-barrier step, no split-K ----------------
// 256 blocks x 512 thr (1/CU). Block = layer (bid>>7) x bg (bid>>5)&3 x cg (bid&31).
// Waves: mfg = wv>>2 (16 batches) x nfg = wv&3 (4 units, 16 gate rows), FULL K per wave.
// Lane owns all 4 gates of (unit u, batch bb) -> pure-register epilogue, no Rbuf.
// Per step: all waves poll producers directly -> load+MFMA+epilogue -> ds_write hstage ->
// ONE sbar_lgkm0 -> wave 0 alone does 64x 32B-sector stores + vmcnt(0) + signal.
// hstage double-buffered (t&1); slot monotonicity makes buffer reuse safe.
__global__ __launch_bounds__(512, 2) void k_persist(
    const float* __restrict__ x,
    const f16* __restrict__ W0, const f16* __restrict__ W1,
    const float* __restrict__ bias0, const float* __restrict__ bias1,
    const int* __restrict__ len,
    f16* __restrict__ h0, f16* __restrict__ h1,
    float* __restrict__ h1f,
    const f16* __restrict__ X0, int pre, int* bar)
{
    extern __shared__ char lds[];          // 128K weights + 2x1K hstage
    char* hstage = lds + 131072;
    const int tid = threadIdx.x;
    const int bid = blockIdx.x;
    const int layer = bid >> 7;
    const int bg = (bid >> 5) & 3;
    const int cg = bid & 31;
    const int wv = tid >> 6, lane = tid & 63;
    const int mfg = wv >> 2, nfg = wv & 3;
    const int l16 = lane & 15, l4 = lane >> 4;

    {   // stage this block's 64 weight rows, frag-major
        const f16* Wsrc = (layer ? W1 : W0) + (size_t)(cg * 64) * 1024;
        #pragma unroll
        for (int j = 0; j < 16; ++j) {
            int cid = j * 512 + tid;
            int r = cid >> 7, kc = cid & 127;
            f16x8 w = *(const f16x8*)(Wsrc + (size_t)r * 1024 + kc * 8);
            int f = (kc >> 6) * 64 + ((kc >> 2) & 15) * 4 + (r >> 4);
            *(f16x8*)(lds + f * 1024 + ((kc & 3) * 16 + (r & 15)) * 16) = w;
        }
    }

    const int bb = bg * 32 + mfg * 16 + l16;       // this lane's batch
    const int u  = cg * 16 + nfg * 4 + l4;         // this lane's h-unit
    const int lb = len[bb];
    float4 bias4 = make_float4(0.f, 0.f, 0.f, 0.f);
    if (layer) bias4 = *(const float4*)(bias1 + u * 4);
    else if (!pre) bias4 = *(const float4*)(bias0 + u * 4);
    float c_s = 0.f;
    f16 h_s = (f16)0.f;

    const char* wb0 = lds + (size_t)nfg * 1024 + lane * 16;          // seg0 (K<512) frags
    const char* wb1 = lds + (size_t)(64 + nfg) * 1024 + lane * 16;   // seg1 (K>=512) frags

    __syncthreads();

    for (int t = 0; t <= T_; ++t) {
        // ---- poll (ALL waves): lanes 0..31 -> L0[bg] slots, 32..63 -> L1[bg] slots ----
        {
            const int which = lane >> 5;
            const int thr = (layer == 0) ? (which ? t - 2 : t) : t;
            int* ap = bar + (which * 4 + bg) * 128 + (lane & 31) * 4;
            while (__any(__hip_atomic_load(ap, __ATOMIC_RELAXED, __HIP_MEMORY_SCOPE_AGENT) < thr))
                __builtin_amdgcn_s_sleep(1);
        }

        const int step = layer ? (t - 1) : t;
        const bool active = (step >= 0) && (step < T_);
        if (active) {
            f32x4 acc = {};
            f16x8 hv[32];
            f16x4 x0v;

            if (layer == 0) {
                const f16* hprev = h0 + (size_t)((t - 1) & 3) * 65536;
                if (pre) {
                    x0v = __builtin_nontemporal_load(
                        (const f16x4*)(X0 + ((size_t)t * 128 + bb) * 2048 + (size_t)u * 4));
                    ldblob16((const char*)hprev + bb * 1024 + l4 * 16, hv);
                    waitvm0();
                    #pragma unroll
                    for (int ks = 0; ks < 16; ++ks) {
                        f16x8 w = *(const f16x8*)(wb1 + ks * 4096);
                        acc = __builtin_amdgcn_mfma_f32_16x16x32_f16(w, hv[ks], acc, 0, 0, 0);
                    }
                } else {
                    // ih on x (f32->f16, compiler-visible loads), K=512
                    const float* xp = x + ((size_t)bb * 512 + t) * 512 + l4 * 8;
                    #pragma unroll
                    for (int ks = 0; ks < 16; ++ks) {
                        const float4 p0 = *(const float4*)(xp + ks * 32);
                        const float4 p1 = *(const float4*)(xp + ks * 32 + 4);
                        f16x8 v = { (f16)p0.x,(f16)p0.y,(f16)p0.z,(f16)p0.w,
                                    (f16)p1.x,(f16)p1.y,(f16)p1.z,(f16)p1.w };
                        f16x8 w = *(const f16x8*)(wb0 + ks * 4096);
                        acc = __builtin_amdgcn_mfma_f32_16x16x32_f16(w, v, acc, 0, 0, 0);
                    }
                    // hh on h0(t-1), K=512
                    ldblob16((const char*)hprev + bb * 1024 + l4 * 16, hv);
                    waitvm0();
                    #pragma unroll
                    for (int ks = 0; ks < 16; ++ks) {
                        f16x8 w = *(const f16x8*)(wb1 + ks * 4096);
                        acc = __builtin_amdgcn_mfma_f32_16x16x32_f16(w, hv[ks], acc, 0, 0, 0);
                    }
                }
            } else {
                const int s = step;
                const f16* srcA = h0 + (size_t)(s & 3) * 65536;          // ih: h0(s)
                const f16* srcB = h1 + (size_t)((s - 1) & 1) * 65536;    // hh: h1(s-1)
                ldblob16((const char*)srcA + bb * 1024 + l4 * 16, hv);
                ldblob16((const char*)srcB + bb * 1024 + l4 * 16, hv + 16);
                waitvm0();
                #pragma unroll
                for (int ks = 0; ks < 16; ++ks) {
                    f16x8 w = *(const f16x8*)(wb0 + ks * 4096);
                    acc = __builtin_amdgcn_mfma_f32_16x16x32_f16(w, hv[ks], acc, 0, 0, 0);
                }
                #pragma unroll
                for (int ks = 0; ks < 16; ++ks) {
                    f16x8 w = *(const f16x8*)(wb1 + ks * 4096);
                    acc = __builtin_amdgcn_mfma_f32_16x16x32_f16(w, hv[16 + ks], acc, 0, 0, 0);
                }
            }

            // ---- pure-register epilogue: lane has gates (i,f,g,o) of (u, bb) ----
            float g0, g1, g2, g3;
            if (layer == 0 && pre) {
                g0 = (float)x0v[0]; g1 = (float)x0v[1]; g2 = (float)x0v[2]; g3 = (float)x0v[3];
            } else {
                g0 = bias4.x; g1 = bias4.y; g2 = bias4.z; g3 = bias4.w;
            }
            const float gi = acc[0] + g0, gf = acc[1] + g1;
            const float gg = acc[2] + g2, go = acc[3] + g3;
            const float cn = (1.f / (1.f + expf(-gf))) * c_s
                           + (1.f / (1.f + expf(-gi))) * tanhf(gg);
            const float hn = (1.f / (1.f + expf(-go))) * tanhf(cn);
            if (step < lb) { c_s = cn; h_s = (f16)hn; }
            *(f16*)(hstage + (t & 1) * 1024 + (mfg * 16 + l16) * 32 + (nfg * 4 + l4) * 2) = h_s;
            if (layer == 1 && step == lb - 1)
                h1f[(size_t)bb * 512 + u] = hn;
        }

        sbar_lgkm0();                      // hstage visible (only barrier in the step)

        if (wv == 0) {                     // wave 0: publish h + signal
            if (active) {
                f16* hw = (layer == 0) ? (h0 + (size_t)(t & 3) * 65536)
                                       : (h1 + (size_t)(step & 1) * 65536);
                const int bl = lane >> 1, half = lane & 1;
                f16x8 v = *(const f16x8*)(hstage + (t & 1) * 1024 + bl * 32 + half * 16);
                stwt16((char*)hw + (size_t)(bg * 32 + bl) * 1024 + cg * 32 + half * 16, v);
            }
            waitvm0();
            if (lane == 0)
                __hip_atomic_store(bar + (layer * 4 + bg) * 128 + cg * 4, t + 1,
                                   __ATOMIC_RELAXED, __HIP_MEMORY_SCOPE_AGENT);
        }
    }
}

// ---------------- final FC ----------------
__global__ __launch_bounds__(256) void k_fc(const float* __restrict__ h1f,
                                            const float* __restrict__ wfc,
                                            const float* __restrict__ bfc,
                                            float* __restrict__ out) {
    int b = blockIdx.x;
    float s0 = 0, s1 = 0, s2 = 0, s3 = 0;
    for (int h = threadIdx.x; h < 512; h += 256) {
        float v = h1f[(size_t)b * 512 + h];
        s0 += v * wfc[h];
        s1 += v * wfc[512 + h];
        s2 += v * wfc[1024 + h];
        s3 += v * wfc[1536 + h];
    }
    #pragma unroll
    for (int off = 32; off; off >>= 1) {
        s0 += __shfl_down(s0, off);
        s1 += __shfl_down(s1, off);
        s2 += __shfl_down(s2, off);
        s3 += __shfl_down(s3, off);
    }
    __shared__ float red[4][4];
    int wid = threadIdx.x >> 6;
    if ((threadIdx.x & 63) == 0) { red[wid][0] = s0; red[wid][1] = s1; red[wid][2] = s2; red[wid][3] = s3; }
    __syncthreads();
    if (threadIdx.x < 4) {
        float s = red[0][threadIdx.x] + red[1][threadIdx.x] + red[2][threadIdx.x] + red[3][threadIdx.x]
                + bfc[threadIdx.x];
        out[b * 4 + threadIdx.x] = s;
    }
}

extern "C" void kernel_launch(void* const* d_in, const int* in_sizes, int n_in,
                              void* d_out, int out_size, void* d_ws, size_t ws_size,
                              hipStream_t stream) {
    const float* x    = (const float*)d_in[0];
    const float* wih0 = (const float*)d_in[1];
    const float* whh0 = (const float*)d_in[2];
    const float* bih0 = (const float*)d_in[3];
    const float* bhh0 = (const float*)d_in[4];
    const float* wih1 = (const float*)d_in[5];
    const float* whh1 = (const float*)d_in[6];
    const float* bih1 = (const float*)d_in[7];
    const float* bhh1 = (const float*)d_in[8];
    const float* wfc  = (const float*)d_in[9];
    const float* bfc  = (const float*)d_in[10];

    if (ws_size < WS_BASE) return;
    const int pre = (ws_size >= WS_PRE) ? 1 : 0;

    char* ws = (char*)d_ws;
    int*   bar   = (int*)(ws + OFF_BAR);
    int*   len   = (int*)(ws + OFF_LEN);
    float* bias0 = (float*)(ws + OFF_BIAS0);
    float* bias1 = (float*)(ws + OFF_BIAS1);
    f16*   W0    = (f16*)(ws + OFF_W0);
    f16*   W1    = (f16*)(ws + OFF_W1);
    f16*   h0    = (f16*)(ws + OFF_H0);
    f16*   h1    = (f16*)(ws + OFF_H1);
    float* h1f   = (float*)(ws + OFF_H1F);
    f16*   X0p   = (f16*)(ws + OFF_X0);

    hipMemsetAsync(ws, 0, 8192, stream);                        // barrier slots + len
    hipMemsetAsync(ws + OFF_H0, 0, WS_BASE - OFF_H0, stream);   // h state + h1f

    k_len<<<dim3(B_, 4), 512, 0, stream>>>(x, len);
    k_wcvt<<<2048, 256, 0, stream>>>(wih0, whh0, bih0, bhh0, W0, bias0);
    k_wcvt<<<2048, 256, 0, stream>>>(wih1, whh1, bih1, bhh1, W1, bias1);
    if (pre) {
        hipFuncSetAttribute((const void*)k_xgemm, hipFuncAttributeMaxDynamicSharedMemorySize, 139264);
        k_xgemm<<<dim3(128, 8), 256, 139264, stream>>>(x, W0, bias0, X0p);
    }

    hipFuncSetAttribute((const void*)k_persist, hipFuncAttributeMaxDynamicSharedMemorySize, 133120);
    const f16* X0c = X0p;
    void* kargs[] = {
        (void*)&x, (void*)&W0, (void*)&W1, (void*)&bias0, (void*)&bias1, (void*)&len,
        (void*)&h0, (void*)&h1, (void*)&h1f,
        (void*)&X0c, (void*)&pre, (void*)&bar
    };
    hipLaunchCooperativeKernel((const void*)k_persist, dim3(NBLK), dim3(512),
                               kargs, 133120, stream);

    k_fc<<<B_, 256, 0, stream>>>(h1f, wfc, bfc, (float*)d_out);
}

// Round 14
// 4484.595 us; speedup vs baseline: 1.4157x; 1.4157x over previous
//
#include <hip/hip_runtime.h>
#include <hip/hip_fp16.h>

typedef _Float16 f16;
typedef _Float16 f16x8 __attribute__((ext_vector_type(8)));
typedef _Float16 f16x4 __attribute__((ext_vector_type(4)));
typedef float f32x4 __attribute__((ext_vector_type(4)));

#define B_ 128
#define T_ 512
#define NBLK 256

// ---------------- workspace layout (bytes) ----------------
static constexpr size_t OFF_BAR   = 0;                         // 8 groups x 32 slots x 16B = 4KB
static constexpr size_t OFF_LEN   = 4096;                      // 128 int
static constexpr size_t OFF_BIAS0 = 8192;                      // 2048 f32
static constexpr size_t OFF_BIAS1 = 16384;                     // 2048 f32
static constexpr size_t OFF_W0    = 32768;                     // 2048x1024 f16, rows u*4+g, [w_ih|w_hh]
static constexpr size_t OFF_W1    = OFF_W0 + 4u*1024u*1024u;
static constexpr size_t OFF_H0    = OFF_W1 + 4u*1024u*1024u;   // 4 bufs x 128x512 f16
static constexpr size_t OFF_H1    = OFF_H0 + 4u*131072u;       // 2 bufs x 128x512 f16
static constexpr size_t OFF_H1F   = OFF_H1 + 2u*131072u;       // 128x512 f32
static constexpr size_t WS_BASE   = OFF_H1F + 262144;
static constexpr size_t OFF_X0    = WS_BASE;                   // f16 [T][B][2048]
static constexpr size_t X0_SZ     = (size_t)T_ * 128 * 2048 * 2;
static constexpr size_t WS_PRE    = OFF_X0 + X0_SZ;

// ---- batched mall-coherent load blob (issue -> IMMEDIATE waitvm0; never defer).
// Max 16 blobs (64 VGPR) per wave — 32 spills to scratch (round 13 regression).
__device__ __forceinline__ void ldblob16(const void* p, f16x8* v) {
    asm volatile(
        "global_load_dwordx4 %0, %16, off offset:0 sc0 sc1\n\t"
        "global_load_dwordx4 %1, %16, off offset:64 sc0 sc1\n\t"
        "global_load_dwordx4 %2, %16, off offset:128 sc0 sc1\n\t"
        "global_load_dwordx4 %3, %16, off offset:192 sc0 sc1\n\t"
        "global_load_dwordx4 %4, %16, off offset:256 sc0 sc1\n\t"
        "global_load_dwordx4 %5, %16, off offset:320 sc0 sc1\n\t"
        "global_load_dwordx4 %6, %16, off offset:384 sc0 sc1\n\t"
        "global_load_dwordx4 %7, %16, off offset:448 sc0 sc1\n\t"
        "global_load_dwordx4 %8, %16, off offset:512 sc0 sc1\n\t"
        "global_load_dwordx4 %9, %16, off offset:576 sc0 sc1\n\t"
        "global_load_dwordx4 %10, %16, off offset:640 sc0 sc1\n\t"
        "global_load_dwordx4 %11, %16, off offset:704 sc0 sc1\n\t"
        "global_load_dwordx4 %12, %16, off offset:768 sc0 sc1\n\t"
        "global_load_dwordx4 %13, %16, off offset:832 sc0 sc1\n\t"
        "global_load_dwordx4 %14, %16, off offset:896 sc0 sc1\n\t"
        "global_load_dwordx4 %15, %16, off offset:960 sc0 sc1"
        : "=&v"(v[0]), "=&v"(v[1]), "=&v"(v[2]), "=&v"(v[3]),
          "=&v"(v[4]), "=&v"(v[5]), "=&v"(v[6]), "=&v"(v[7]),
          "=&v"(v[8]), "=&v"(v[9]), "=&v"(v[10]), "=&v"(v[11]),
          "=&v"(v[12]), "=&v"(v[13]), "=&v"(v[14]), "=&v"(v[15])
        : "v"(p) : "memory");
}
__device__ __forceinline__ void waitvm0() {
    asm volatile("s_waitcnt vmcnt(0)" ::: "memory");
    __builtin_amdgcn_sched_barrier(0);
}
__device__ __forceinline__ void stwt16(void* p, f16x8 v) {
    asm volatile("global_store_dwordx4 %0, %1, off sc0 sc1" :: "v"(p), "v"(v) : "memory");
}
__device__ __forceinline__ void pollge(int* ap, int thr) {
    while (__any(__hip_atomic_load(ap, __ATOMIC_RELAXED, __HIP_MEMORY_SCOPE_AGENT) < thr))
        __builtin_amdgcn_s_sleep(1);
}

// ---------------- lengths ----------------
__global__ __launch_bounds__(512) void k_len(const float* __restrict__ x, int* __restrict__ len) {
    int b = blockIdx.x, q = blockIdx.y;
    int rl = threadIdx.x >> 2, part = threadIdx.x & 3;
    const float4* p = (const float4*)(x + ((size_t)b * T_ + q * 128 + rl) * 512 + part * 128);
    float s = 0.f;
    #pragma unroll
    for (int i = 0; i < 32; ++i) { float4 v = p[i]; s += v.x + v.y + v.z + v.w; }
    s += __shfl_xor(s, 1);
    s += __shfl_xor(s, 2);
    int cnt = __syncthreads_count(part == 0 && s != 0.0f);
    if (threadIdx.x == 0) atomicAdd(&len[b], cnt);
}

// ---------------- weight convert: rows u*4+gate, [w_ih|w_hh], f32->f16 ----------------
__global__ __launch_bounds__(256) void k_wcvt(const float* __restrict__ wih, const float* __restrict__ whh,
                                              const float* __restrict__ bih, const float* __restrict__ bhh,
                                              f16* __restrict__ W, float* __restrict__ bias) {
    int r = blockIdx.x;
    int h = r >> 2, g = r & 3;
    int src = g * 512 + h;
    const float* a = wih + (size_t)src * 512;
    const float* bsrc = whh + (size_t)src * 512;
    f16* dst = W + (size_t)r * 1024;
    #pragma unroll
    for (int j = 0; j < 2; ++j) {
        int k = threadIdx.x + j * 256;
        dst[k]       = (f16)a[k];
        dst[k + 512] = (f16)bsrc[k];
    }
    if (threadIdx.x == 0) bias[r] = bih[src] + bhh[src];
}

// ---------------- X0 precompute, x-stationary ----------------
__global__ __launch_bounds__(256) void k_xgemm(const float* __restrict__ x, const f16* __restrict__ W0,
                                               const float* __restrict__ bias0, f16* __restrict__ X0) {
    extern __shared__ char lds[];          // 64K xtile + 64K wtile + 8K outstage
    char* xt = lds;
    char* wt = lds + 65536;
    char* ot = lds + 131072;
    const int b = blockIdx.x, tc = blockIdx.y;
    const int tid = threadIdx.x;
    const int tf = tid >> 6, lane = tid & 63;
    const int l16 = lane & 15, l4 = lane >> 4;

    {   // stage x tile: B-operand frag-major
        const int t = tid >> 2, q = tid & 3;
        const float* src = x + ((size_t)b * 512 + tc * 64 + t) * 512 + q * 128;
        #pragma unroll
        for (int j = 0; j < 16; ++j) {
            const float4 p0 = *(const float4*)(src + j * 8);
            const float4 p1 = *(const float4*)(src + j * 8 + 4);
            f16x8 v = { (f16)p0.x,(f16)p0.y,(f16)p0.z,(f16)p0.w,
                        (f16)p1.x,(f16)p1.y,(f16)p1.z,(f16)p1.w };
            const int k = q * 128 + j * 8;
            *(f16x8*)(xt + ((t >> 4) * 16 + (k >> 5)) * 1024
                         + ((t & 15) + ((k >> 3) & 3) * 16) * 16) = v;
        }
    }
    __syncthreads();

    for (int cg = 0; cg < 32; ++cg) {
        {   // stage W tile (ih half), A-operand frag-major
            const int r = tid >> 2, q = tid & 3;
            const f16* src = W0 + (size_t)(cg * 64 + r) * 1024 + q * 128;
            #pragma unroll
            for (int j = 0; j < 16; ++j) {
                f16x8 w = *(const f16x8*)(src + j * 8);
                const int k = q * 128 + j * 8;
                *(f16x8*)(wt + ((k >> 5) * 4 + (r >> 4)) * 1024
                             + ((r & 15) + ((k >> 3) & 3) * 16) * 16) = w;
            }
        }
        __syncthreads();
        f32x4 acc[4] = {};
        #pragma unroll
        for (int ks = 0; ks < 16; ++ks) {
            f16x8 bx = *(const f16x8*)(xt + (tf * 16 + ks) * 1024 + lane * 16);
            #pragma unroll
            for (int nf = 0; nf < 4; ++nf) {
                f16x8 aw = *(const f16x8*)(wt + (ks * 4 + nf) * 1024 + lane * 16);
                acc[nf] = __builtin_amdgcn_mfma_f32_16x16x32_f16(aw, bx, acc[nf], 0, 0, 0);
            }
        }
        {   // bias + pack to outstage (swizzled)
            const int t = tf * 16 + l16;
            const int sw = (t & 7) << 4;
            #pragma unroll
            for (int nf = 0; nf < 4; ++nf) {
                const float4 b4 = *(const float4*)(bias0 + cg * 64 + nf * 16 + l4 * 4);
                f16x4 v = { (f16)(acc[nf][0] + b4.x), (f16)(acc[nf][1] + b4.y),
                            (f16)(acc[nf][2] + b4.z), (f16)(acc[nf][3] + b4.w) };
                const int byte = t * 128 + nf * 32 + l4 * 8;
                *(f16x4*)(ot + (byte ^ sw)) = v;
            }
        }
        __syncthreads();
        {   // coalesced NT store
            const int t = tid >> 2, ch = tid & 3;
            const int sw = (t & 7) << 4;
            const int byte = t * 128 + ch * 32;
            f16x8 v0 = *(const f16x8*)(ot + (byte ^ sw));
            f16x8 v1 = *(const f16x8*)(ot + ((byte + 16) ^ sw));
            f16* dst = X0 + ((size_t)(tc * 64 + t) * 128 + b) * 2048 + cg * 64 + ch * 16;
            __builtin_nontemporal_store(v0, (f16x8*)dst);
            __builtin_nontemporal_store(v1, (f16x8*)(dst + 8));
        }
        __syncthreads();
    }
}

// ---------------- persistent kernel ----------------
// 256 blocks x 512 thr (1/CU). Block = layer (bid>>7) x bg (bid>>5)&3 x cg (bid&31).
// L0 (pre): NO split-K — waves mfg(2) x nfg(4), full K=512 (hh), hv[16]=64 VGPR;
//   pure-register epilogue, ONE barrier/step. Per-wave polls (own thr t / L1 guard t-2).
// L1: kh split as round 9, but per-wave polls: kh0 waves poll L0 (thr t) and start
//   h0-load + ih MFMAs while own-group signal is in flight; kh1 waves poll own (thr t).
//   Two barriers/step (Rbuf, hstage). hstage double-buffered (t&1).
__global__ __launch_bounds__(512, 2) void k_persist(
    const float* __restrict__ x,
    const f16* __restrict__ W0, const f16* __restrict__ W1,
    const float* __restrict__ bias0, const float* __restrict__ bias1,
    const int* __restrict__ len,
    f16* __restrict__ h0, f16* __restrict__ h1,
    float* __restrict__ h1f,
    const f16* __restrict__ X0, int pre, int* bar)
{
    extern __shared__ char lds[];          // 128K weights + 8K Rbuf + 2x1K hstage
    char* Rbuf    = lds + 131072;
    char* hstage0 = lds + 139264;
    const int tid = threadIdx.x;
    const int bid = blockIdx.x;
    const int layer = bid >> 7;
    const int bg = (bid >> 5) & 3;
    const int cg = bid & 31;
    const int wv = tid >> 6, lane = tid & 63;
    const int l16 = lane & 15, l4 = lane >> 4;

    {   // stage this block's 64 weight rows, frag-major
        const f16* Wsrc = (layer ? W1 : W0) + (size_t)(cg * 64) * 1024;
        #pragma unroll
        for (int j = 0; j < 16; ++j) {
            int cid = j * 512 + tid;
            int r = cid >> 7, kc = cid & 127;
            f16x8 w = *(const f16x8*)(Wsrc + (size_t)r * 1024 + kc * 8);
            int f = (kc >> 6) * 64 + ((kc >> 2) & 15) * 4 + (r >> 4);
            *(f16x8*)(lds + f * 1024 + ((kc & 3) * 16 + (r & 15)) * 16) = w;
        }
    }
    __syncthreads();

    if (layer == 0) {
        // ---------------- layer 0 ----------------
        const int mfg = wv >> 2, nfg = wv & 3;
        const int bb = bg * 32 + mfg * 16 + l16;
        const int u  = cg * 16 + nfg * 4 + l4;
        const int lb = len[bb];
        float4 bias4 = make_float4(0.f, 0.f, 0.f, 0.f);
        if (!pre) bias4 = *(const float4*)(bias0 + u * 4);
        float c_s = 0.f;
        f16 h_s = (f16)0.f;
        const char* wb0 = lds + (size_t)nfg * 1024 + lane * 16;          // w_ih frags
        const char* wb1 = lds + (size_t)(64 + nfg) * 1024 + lane * 16;   // w_hh frags

        for (int t = 0; t <= T_; ++t) {
            {   // per-wave poll: lanes<32 own L0 group (thr t); lanes>=32 L1 lap-guard (t-2)
                const int which = lane >> 5;
                pollge(bar + (which * 4 + bg) * 128 + (lane & 31) * 4, which ? t - 2 : t);
            }
            const bool active = t < T_;
            if (active) {
                f32x4 acc = {};
                f16x8 hv[16];
                f16x4 x0v;
                const f16* hprev = h0 + (size_t)((t - 1) & 3) * 65536;
                if (pre) {
                    x0v = __builtin_nontemporal_load(
                        (const f16x4*)(X0 + ((size_t)t * 128 + bb) * 2048 + (size_t)u * 4));
                    ldblob16((const char*)hprev + bb * 1024 + l4 * 16, hv);
                    waitvm0();
                    #pragma unroll
                    for (int ks = 0; ks < 16; ++ks) {
                        f16x8 w = *(const f16x8*)(wb1 + ks * 4096);
                        acc = __builtin_amdgcn_mfma_f32_16x16x32_f16(w, hv[ks], acc, 0, 0, 0);
                    }
                } else {
                    const float* xp = x + ((size_t)bb * 512 + t) * 512 + l4 * 8;
                    #pragma unroll
                    for (int ks = 0; ks < 16; ++ks) {
                        const float4 p0 = *(const float4*)(xp + ks * 32);
                        const float4 p1 = *(const float4*)(xp + ks * 32 + 4);
                        f16x8 v = { (f16)p0.x,(f16)p0.y,(f16)p0.z,(f16)p0.w,
                                    (f16)p1.x,(f16)p1.y,(f16)p1.z,(f16)p1.w };
                        f16x8 w = *(const f16x8*)(wb0 + ks * 4096);
                        acc = __builtin_amdgcn_mfma_f32_16x16x32_f16(w, v, acc, 0, 0, 0);
                    }
                    ldblob16((const char*)hprev + bb * 1024 + l4 * 16, hv);
                    waitvm0();
                    #pragma unroll
                    for (int ks = 0; ks < 16; ++ks) {
                        f16x8 w = *(const f16x8*)(wb1 + ks * 4096);
                        acc = __builtin_amdgcn_mfma_f32_16x16x32_f16(w, hv[ks], acc, 0, 0, 0);
                    }
                }
                float g0, g1, g2, g3;
                if (pre) { g0 = (float)x0v[0]; g1 = (float)x0v[1]; g2 = (float)x0v[2]; g3 = (float)x0v[3]; }
                else     { g0 = bias4.x; g1 = bias4.y; g2 = bias4.z; g3 = bias4.w; }
                const float gi = acc[0] + g0, gf = acc[1] + g1;
                const float gg = acc[2] + g2, go = acc[3] + g3;
                const float cn = (1.f / (1.f + expf(-gf))) * c_s
                               + (1.f / (1.f + expf(-gi))) * tanhf(gg);
                const float hn = (1.f / (1.f + expf(-go))) * tanhf(cn);
                if (t < lb) { c_s = cn; h_s = (f16)hn; }
                *(f16*)(hstage0 + (t & 1) * 1024 + (mfg * 16 + l16) * 32 + (nfg * 4 + l4) * 2) = h_s;
            }
            __syncthreads();
            if (wv == 0) {
                if (active) {
                    f16* hw = h0 + (size_t)(t & 3) * 65536;
                    const int bl = lane >> 1, half = lane & 1;
                    f16x8 v = *(const f16x8*)(hstage0 + (t & 1) * 1024 + bl * 32 + half * 16);
                    stwt16((char*)hw + (size_t)(bg * 32 + bl) * 1024 + cg * 32 + half * 16, v);
                }
                waitvm0();
                if (lane == 0)
                    __hip_atomic_store(bar + bg * 128 + cg * 4, t + 1,
                                       __ATOMIC_RELAXED, __HIP_MEMORY_SCOPE_AGENT);
            }
        }
    } else {
        // ---------------- layer 1 ----------------
        const int kh = wv & 1, mfg = (wv >> 1) & 1, nfg = wv >> 2;
        const int bb = bg * 32 + mfg * 16 + l16;
        const int lb = len[bb];
        float4 bias4[2];
        #pragma unroll
        for (int ni = 0; ni < 2; ++ni)
            bias4[ni] = *(const float4*)(bias1 + (cg * 16 + (nfg * 2 + ni) * 4 + l4) * 4);
        float c_s[2] = {};
        f16 h_s[2] = {};

        for (int t = 0; t <= T_; ++t) {
            // per-wave poll: kh0 needs h0(s) -> L0 slots >= t ; kh1 needs h1(s-1) -> own >= t
            pollge(bar + ((kh ? 4 : 0) + bg) * 128 + (lane & 31) * 4, t);

            const int step = t - 1;
            const bool active = (step >= 0) && (step < T_);
            f32x4 acc[2] = {};
            if (active) {
                f16x8 hv[16];
                const int s = step;
                const f16* src = (kh == 0) ? (h0 + (size_t)(s & 3) * 65536)        // ih: h0(s)
                                           : (h1 + (size_t)((s - 1) & 1) * 65536); // hh: h1(s-1)
                ldblob16((const char*)src + bb * 1024 + l4 * 16, hv);
                waitvm0();
                const char* wb = lds + (size_t)(kh * 64 + nfg * 2) * 1024 + lane * 16;
                #pragma unroll
                for (int ks = 0; ks < 16; ++ks) {
                    f16x8 w0 = *(const f16x8*)(wb + ks * 4096);
                    f16x8 w1 = *(const f16x8*)(wb + ks * 4096 + 1024);
                    acc[0] = __builtin_amdgcn_mfma_f32_16x16x32_f16(w0, hv[ks], acc[0], 0, 0, 0);
                    acc[1] = __builtin_amdgcn_mfma_f32_16x16x32_f16(w1, hv[ks], acc[1], 0, 0, 0);
                }
                if (kh == 1) {
                    #pragma unroll
                    for (int ni = 0; ni < 2; ++ni)
                        *(f32x4*)(Rbuf + (((mfg * 2 + nfg) * 2 + ni) * 64 + lane) * 16) = acc[ni];
                }
            }
            __syncthreads();                       // Rbuf visible
            if (active && kh == 0) {
                #pragma unroll
                for (int ni = 0; ni < 2; ++ni)
                    acc[ni] += *(const f32x4*)(Rbuf + (((mfg * 2 + nfg) * 2 + ni) * 64 + lane) * 16);
                const bool msk = step < lb;
                #pragma unroll
                for (int ni = 0; ni < 2; ++ni) {
                    const float gi = acc[ni][0] + bias4[ni].x, gf = acc[ni][1] + bias4[ni].y;
                    const float gg = acc[ni][2] + bias4[ni].z, go = acc[ni][3] + bias4[ni].w;
                    const float cn = (1.f / (1.f + expf(-gf))) * c_s[ni]
                                   + (1.f / (1.f + expf(-gi))) * tanhf(gg);
                    const float hn = (1.f / (1.f + expf(-go))) * tanhf(cn);
                    if (msk) { c_s[ni] = cn; h_s[ni] = (f16)hn; }
                    *(f16*)(hstage0 + (t & 1) * 1024
                            + (mfg * 16 + l16) * 32 + ((nfg * 2 + ni) * 4 + l4) * 2) = h_s[ni];
                    if (step == lb - 1)
                        h1f[(size_t)bb * 512 + cg * 16 + (nfg * 2 + ni) * 4 + l4] = hn;
                }
            }
            __syncthreads();                       // hstage visible
            if (wv == 0) {
                if (active) {
                    f16* hw = h1 + (size_t)(step & 1) * 65536;
                    const int bl = lane >> 1, half = lane & 1;
                    f16x8 v = *(const f16x8*)(hstage0 + (t & 1) * 1024 + bl * 32 + half * 16);
                    stwt16((char*)hw + (size_t)(bg * 32 + bl) * 1024 + cg * 32 + half * 16, v);
                }
                waitvm0();
                if (lane == 0)
                    __hip_atomic_store(bar + (4 + bg) * 128 + cg * 4, t + 1,
                                       __ATOMIC_RELAXED, __HIP_MEMORY_SCOPE_AGENT);
            }
        }
    }
}

// ---------------- final FC ----------------
__global__ __launch_bounds__(256) void k_fc(const float* __restrict__ h1f,
                                            const float* __restrict__ wfc,
                                            const float* __restrict__ bfc,
                                            float* __restrict__ out) {
    int b = blockIdx.x;
    float s0 = 0, s1 = 0, s2 = 0, s3 = 0;
    for (int h = threadIdx.x; h < 512; h += 256) {
        float v = h1f[(size_t)b * 512 + h];
        s0 += v * wfc[h];
        s1 += v * wfc[512 + h];
        s2 += v * wfc[1024 + h];
        s3 += v * wfc[1536 + h];
    }
    #pragma unroll
    for (int off = 32; off; off >>= 1) {
        s0 += __shfl_down(s0, off);
        s1 += __shfl_down(s1, off);
        s2 += __shfl_down(s2, off);
        s3 += __shfl_down(s3, off);
    }
    __shared__ float red[4][4];
    int wid = threadIdx.x >> 6;
    if ((threadIdx.x & 63) == 0) { red[wid][0] = s0; red[wid][1] = s1; red[wid][2] = s2; red[wid][3] = s3; }
    __syncthreads();
    if (threadIdx.x < 4) {
        float s = red[0][threadIdx.x] + red[1][threadIdx.x] + red[2][threadIdx.x] + red[3][threadIdx.x]
                + bfc[threadIdx.x];
        out[b * 4 + threadIdx.x] = s;
    }
}

extern "C" void kernel_launch(void* const* d_in, const int* in_sizes, int n_in,
                              void* d_out, int out_size, void* d_ws, size_t ws_size,
                              hipStream_t stream) {
    const float* x    = (const float*)d_in[0];
    const float* wih0 = (const float*)d_in[1];
    const float* whh0 = (const float*)d_in[2];
    const float* bih0 = (const float*)d_in[3];
    const float* bhh0 = (const float*)d_in[4];
    const float* wih1 = (const float*)d_in[5];
    const float* whh1 = (const float*)d_in[6];
    const float* bih1 = (const float*)d_in[7];
    const float* bhh1 = (const float*)d_in[8];
    const float* wfc  = (const float*)d_in[9];
    const float* bfc  = (const float*)d_in[10];

    if (ws_size < WS_BASE) return;
    const int pre = (ws_size >= WS_PRE) ? 1 : 0;

    char* ws = (char*)d_ws;
    int*   bar   = (int*)(ws + OFF_BAR);
    int*   len   = (int*)(ws + OFF_LEN);
    float* bias0 = (float*)(ws + OFF_BIAS0);
    float* bias1 = (float*)(ws + OFF_BIAS1);
    f16*   W0    = (f16*)(ws + OFF_W0);
    f16*   W1    = (f16*)(ws + OFF_W1);
    f16*   h0    = (f16*)(ws + OFF_H0);
    f16*   h1    = (f16*)(ws + OFF_H1);
    float* h1f   = (float*)(ws + OFF_H1F);
    f16*   X0p   = (f16*)(ws + OFF_X0);

    hipMemsetAsync(ws, 0, 8192, stream);                        // barrier slots + len
    hipMemsetAsync(ws + OFF_H0, 0, WS_BASE - OFF_H0, stream);   // h state + h1f

    k_len<<<dim3(B_, 4), 512, 0, stream>>>(x, len);
    k_wcvt<<<2048, 256, 0, stream>>>(wih0, whh0, bih0, bhh0, W0, bias0);
    k_wcvt<<<2048, 256, 0, stream>>>(wih1, whh1, bih1, bhh1, W1, bias1);
    if (pre) {
        hipFuncSetAttribute((const void*)k_xgemm, hipFuncAttributeMaxDynamicSharedMemorySize, 139264);
        k_xgemm<<<dim3(128, 8), 256, 139264, stream>>>(x, W0, bias0, X0p);
    }

    hipFuncSetAttribute((const void*)k_persist, hipFuncAttributeMaxDynamicSharedMemorySize, 141312);
    const f16* X0c = X0p;
    void* kargs[] = {
        (void*)&x, (void*)&W0, (void*)&W1, (void*)&bias0, (void*)&bias1, (void*)&len,
        (void*)&h0, (void*)&h1, (void*)&h1f,
        (void*)&X0c, (void*)&pre, (void*)&bar
    };
    hipLaunchCooperativeKernel((const void*)k_persist, dim3(NBLK), dim3(512),
                               kargs, 141312, stream);

    k_fc<<<B_, 256, 0, stream>>>(h1f, wfc, bfc, (float*)d_out);
}

// Round 16
// 3647.679 us; speedup vs baseline: 1.7406x; 1.2294x over previous
//
#include <hip/hip_runtime.h>
#include <hip/hip_fp16.h>

typedef _Float16 f16;
typedef _Float16 f16x8 __attribute__((ext_vector_type(8)));
typedef _Float16 f16x4 __attribute__((ext_vector_type(4)));
typedef float f32x4 __attribute__((ext_vector_type(4)));

#define B_ 128
#define T_ 512
#define NBLK 256

// ---------------- workspace layout (bytes) ----------------
static constexpr size_t OFF_BAR   = 0;                         // 8 groups x 32 slots x 16B = 4KB
static constexpr size_t OFF_LEN   = 4096;                      // 128 int
static constexpr size_t OFF_BIAS0 = 8192;                      // 2048 f32
static constexpr size_t OFF_BIAS1 = 16384;                     // 2048 f32
static constexpr size_t OFF_W0    = 32768;                     // 2048x1024 f16, rows u*4+g, [w_ih|w_hh]
static constexpr size_t OFF_W1    = OFF_W0 + 4u*1024u*1024u;
static constexpr size_t OFF_H0    = OFF_W1 + 4u*1024u*1024u;   // 4 bufs x 128x512 f16
static constexpr size_t OFF_H1    = OFF_H0 + 4u*131072u;       // 2 bufs x 128x512 f16
static constexpr size_t OFF_H1F   = OFF_H1 + 2u*131072u;       // 128x512 f32
static constexpr size_t WS_BASE   = OFF_H1F + 262144;
static constexpr size_t OFF_X0    = WS_BASE;                   // f16 [T][B][2048]
static constexpr size_t X0_SZ     = (size_t)T_ * 128 * 2048 * 2;
static constexpr size_t WS_PRE    = OFF_X0 + X0_SZ;

// ---- batched mall-coherent load blobs (issue -> IMMEDIATE waitvm0; never defer).
// Keep per-wave blob footprint <= 32 VGPR (rounds 6/13: spill serializes the blob).
__device__ __forceinline__ void ldblob8(const void* p, f16x8* v) {
    asm volatile(
        "global_load_dwordx4 %0, %8, off offset:0 sc0 sc1\n\t"
        "global_load_dwordx4 %1, %8, off offset:64 sc0 sc1\n\t"
        "global_load_dwordx4 %2, %8, off offset:128 sc0 sc1\n\t"
        "global_load_dwordx4 %3, %8, off offset:192 sc0 sc1\n\t"
        "global_load_dwordx4 %4, %8, off offset:256 sc0 sc1\n\t"
        "global_load_dwordx4 %5, %8, off offset:320 sc0 sc1\n\t"
        "global_load_dwordx4 %6, %8, off offset:384 sc0 sc1\n\t"
        "global_load_dwordx4 %7, %8, off offset:448 sc0 sc1"
        : "=&v"(v[0]), "=&v"(v[1]), "=&v"(v[2]), "=&v"(v[3]),
          "=&v"(v[4]), "=&v"(v[5]), "=&v"(v[6]), "=&v"(v[7])
        : "v"(p) : "memory");
}
__device__ __forceinline__ void ldblob4(const void* p, f16x8* v) {
    asm volatile(
        "global_load_dwordx4 %0, %4, off offset:0 sc0 sc1\n\t"
        "global_load_dwordx4 %1, %4, off offset:64 sc0 sc1\n\t"
        "global_load_dwordx4 %2, %4, off offset:128 sc0 sc1\n\t"
        "global_load_dwordx4 %3, %4, off offset:192 sc0 sc1"
        : "=&v"(v[0]), "=&v"(v[1]), "=&v"(v[2]), "=&v"(v[3])
        : "v"(p) : "memory");
}
__device__ __forceinline__ void waitvm0() {
    asm volatile("s_waitcnt vmcnt(0)" ::: "memory");
    __builtin_amdgcn_sched_barrier(0);
}
__device__ __forceinline__ void stwt16(void* p, f16x8 v) {
    asm volatile("global_store_dwordx4 %0, %1, off sc0 sc1" :: "v"(p), "v"(v) : "memory");
}

// ---------------- lengths ----------------
__global__ __launch_bounds__(512) void k_len(const float* __restrict__ x, int* __restrict__ len) {
    int b = blockIdx.x, q = blockIdx.y;
    int rl = threadIdx.x >> 2, part = threadIdx.x & 3;
    const float4* p = (const float4*)(x + ((size_t)b * T_ + q * 128 + rl) * 512 + part * 128);
    float s = 0.f;
    #pragma unroll
    for (int i = 0; i < 32; ++i) { float4 v = p[i]; s += v.x + v.y + v.z + v.w; }
    s += __shfl_xor(s, 1);
    s += __shfl_xor(s, 2);
    int cnt = __syncthreads_count(part == 0 && s != 0.0f);
    if (threadIdx.x == 0) atomicAdd(&len[b], cnt);
}

// ---------------- weight convert: rows u*4+gate, [w_ih|w_hh], f32->f16 ----------------
__global__ __launch_bounds__(256) void k_wcvt(const float* __restrict__ wih, const float* __restrict__ whh,
                                              const float* __restrict__ bih, const float* __restrict__ bhh,
                                              f16* __restrict__ W, float* __restrict__ bias) {
    int r = blockIdx.x;
    int h = r >> 2, g = r & 3;
    int src = g * 512 + h;
    const float* a = wih + (size_t)src * 512;
    const float* bsrc = whh + (size_t)src * 512;
    f16* dst = W + (size_t)r * 1024;
    #pragma unroll
    for (int j = 0; j < 2; ++j) {
        int k = threadIdx.x + j * 256;
        dst[k]       = (f16)a[k];
        dst[k + 512] = (f16)bsrc[k];
    }
    if (threadIdx.x == 0) bias[r] = bih[src] + bhh[src];
}

// ---------------- X0 precompute, x-stationary ----------------
__global__ __launch_bounds__(256) void k_xgemm(const float* __restrict__ x, const f16* __restrict__ W0,
                                               const float* __restrict__ bias0, f16* __restrict__ X0) {
    extern __shared__ char lds[];          // 64K xtile + 64K wtile + 8K outstage
    char* xt = lds;
    char* wt = lds + 65536;
    char* ot = lds + 131072;
    const int b = blockIdx.x, tc = blockIdx.y;
    const int tid = threadIdx.x;
    const int tf = tid >> 6, lane = tid & 63;
    const int l16 = lane & 15, l4 = lane >> 4;

    {   // stage x tile: B-operand frag-major
        const int t = tid >> 2, q = tid & 3;
        const float* src = x + ((size_t)b * 512 + tc * 64 + t) * 512 + q * 128;
        #pragma unroll
        for (int j = 0; j < 16; ++j) {
            const float4 p0 = *(const float4*)(src + j * 8);
            const float4 p1 = *(const float4*)(src + j * 8 + 4);
            f16x8 v = { (f16)p0.x,(f16)p0.y,(f16)p0.z,(f16)p0.w,
                        (f16)p1.x,(f16)p1.y,(f16)p1.z,(f16)p1.w };
            const int k = q * 128 + j * 8;
            *(f16x8*)(xt + ((t >> 4) * 16 + (k >> 5)) * 1024
                         + ((t & 15) + ((k >> 3) & 3) * 16) * 16) = v;
        }
    }
    __syncthreads();

    for (int cg = 0; cg < 32; ++cg) {
        {   // stage W tile (ih half), A-operand frag-major
            const int r = tid >> 2, q = tid & 3;
            const f16* src = W0 + (size_t)(cg * 64 + r) * 1024 + q * 128;
            #pragma unroll
            for (int j = 0; j < 16; ++j) {
                f16x8 w = *(const f16x8*)(src + j * 8);
                const int k = q * 128 + j * 8;
                *(f16x8*)(wt + ((k >> 5) * 4 + (r >> 4)) * 1024
                             + ((r & 15) + ((k >> 3) & 3) * 16) * 16) = w;
            }
        }
        __syncthreads();
        f32x4 acc[4] = {};
        #pragma unroll
        for (int ks = 0; ks < 16; ++ks) {
            f16x8 bx = *(const f16x8*)(xt + (tf * 16 + ks) * 1024 + lane * 16);
            #pragma unroll
            for (int nf = 0; nf < 4; ++nf) {
                f16x8 aw = *(const f16x8*)(wt + (ks * 4 + nf) * 1024 + lane * 16);
                acc[nf] = __builtin_amdgcn_mfma_f32_16x16x32_f16(aw, bx, acc[nf], 0, 0, 0);
            }
        }
        {   // bias + pack to outstage (swizzled)
            const int t = tf * 16 + l16;
            const int sw = (t & 7) << 4;
            #pragma unroll
            for (int nf = 0; nf < 4; ++nf) {
                const float4 b4 = *(const float4*)(bias0 + cg * 64 + nf * 16 + l4 * 4);
                f16x4 v = { (f16)(acc[nf][0] + b4.x), (f16)(acc[nf][1] + b4.y),
                            (f16)(acc[nf][2] + b4.z), (f16)(acc[nf][3] + b4.w) };
                const int byte = t * 128 + nf * 32 + l4 * 8;
                *(f16x4*)(ot + (byte ^ sw)) = v;
            }
        }
        __syncthreads();
        {   // coalesced NT store
            const int t = tid >> 2, ch = tid & 3;
            const int sw = (t & 7) << 4;
            const int byte = t * 128 + ch * 32;
            f16x8 v0 = *(const f16x8*)(ot + (byte ^ sw));
            f16x8 v1 = *(const f16x8*)(ot + ((byte + 16) ^ sw));
            f16* dst = X0 + ((size_t)(tc * 64 + t) * 128 + b) * 2048 + cg * 64 + ch * 16;
            __builtin_nontemporal_store(v0, (f16x8*)dst);
            __builtin_nontemporal_store(v1, (f16x8*)(dst + 8));
        }
        __syncthreads();
    }
}

// ---------------- persistent kernel (round-9 schedule; 1x-redundant loads) ----------------
// 256 blocks x 512 thr (1/CU). Block = layer (bid>>7) x bg (bid>>5)&3 x cg (bid&31).
// Waves: p = wv&3 (4 K/source partials) x mfg = wv>>2 (16-batch group). Each wave loads a
// DISTINCT slice (1x redundancy) and computes ALL 4 n-frags. Rbuf 4-way reduce (24KB LDS).
// Schedule identical to round 9. h publish: threads 0..63 ONLY (32 rows x 2x16B = the
// block's exact 1KB slice — round 15's tid<128 guard overflowed into neighbor bg rows).
__global__ __launch_bounds__(512, 2) void k_persist(
    const float* __restrict__ x,
    const f16* __restrict__ W0, const f16* __restrict__ W1,
    const float* __restrict__ bias0, const float* __restrict__ bias1,
    const int* __restrict__ len,
    f16* __restrict__ h0, f16* __restrict__ h1,
    float* __restrict__ h1f,
    const f16* __restrict__ X0, int pre, int* bar)
{
    extern __shared__ char lds[];          // 128K weights + 24K Rbuf + 1K hstage
    char* Rbuf   = lds + 131072;
    char* hstage = lds + 155648;
    const int tid = threadIdx.x;
    const int bid = blockIdx.x;
    const int layer = bid >> 7;
    const int bg = (bid >> 5) & 3;
    const int cg = bid & 31;
    const int wv = tid >> 6, lane = tid & 63;
    const int p = wv & 3, mfg = wv >> 2;
    const int l16 = lane & 15, l4 = lane >> 4;

    {   // stage this block's 64 weight rows, frag-major: f = seg*64 + kslot*4 + nf
        const f16* Wsrc = (layer ? W1 : W0) + (size_t)(cg * 64) * 1024;
        #pragma unroll
        for (int j = 0; j < 16; ++j) {
            int cid = j * 512 + tid;
            int r = cid >> 7, kc = cid & 127;
            f16x8 w = *(const f16x8*)(Wsrc + (size_t)r * 1024 + kc * 8);
            int f = (kc >> 6) * 64 + ((kc >> 2) & 15) * 4 + (r >> 4);
            *(f16x8*)(lds + f * 1024 + ((kc & 3) * 16 + (r & 15)) * 16) = w;
        }
    }

    const int bb = bg * 32 + mfg * 16 + l16;       // this lane's batch
    const int lb = len[bb];
    float4 bias4[4];
    #pragma unroll
    for (int nf = 0; nf < 4; ++nf) {
        const int u = cg * 16 + nf * 4 + l4;
        if (layer) bias4[nf] = *(const float4*)(bias1 + u * 4);
        else if (!pre) bias4[nf] = *(const float4*)(bias0 + u * 4);
        else bias4[nf] = make_float4(0.f, 0.f, 0.f, 0.f);
    }
    float c_s[4] = {};
    f16 h_s[4] = {};

    __syncthreads();

    for (int t = 0; t <= T_; ++t) {
        // ---- poll (wave 0): lanes 0..31 -> L0[bg] slots, 32..63 -> L1[bg] slots ----
        if (tid < 64) {
            const int which = tid >> 5;
            const int thr = (layer == 0) ? (which ? t - 2 : t) : t;
            int* ap = bar + (which * 4 + bg) * 128 + (tid & 31) * 4;
            while (__any(__hip_atomic_load(ap, __ATOMIC_RELAXED, __HIP_MEMORY_SCOPE_AGENT) < thr))
                __builtin_amdgcn_s_sleep(1);
        }
        __syncthreads();

        const int step = layer ? (t - 1) : t;
        const bool active = (step >= 0) && (step < T_);
        f32x4 acc[4] = {};
        f16x4 x0v[4];

        if (active) {
            f16x8 hv[8];
            if (layer == 0) {
                const f16* hprev = h0 + (size_t)((t - 1) & 3) * 65536;
                if (pre) {
                    if (p == 0) {        // X0 for epilogue: compiler-visible NT loads, early
                        #pragma unroll
                        for (int nf = 0; nf < 4; ++nf)
                            x0v[nf] = __builtin_nontemporal_load(
                                (const f16x4*)(X0 + ((size_t)t * 128 + bb) * 2048
                                               + (size_t)(cg * 16 + nf * 4 + l4) * 4));
                    }
                    // hh: this wave's K-quarter [p*128, p*128+128)
                    ldblob4((const char*)hprev + bb * 1024 + p * 256 + l4 * 16, hv);
                    waitvm0();
                    #pragma unroll
                    for (int ks = 0; ks < 4; ++ks) {
                        #pragma unroll
                        for (int nf = 0; nf < 4; ++nf) {
                            f16x8 w = *(const f16x8*)(lds + (size_t)(64 + (p * 4 + ks) * 4 + nf) * 1024
                                                      + lane * 16);
                            acc[nf] = __builtin_amdgcn_mfma_f32_16x16x32_f16(w, hv[ks], acc[nf], 0, 0, 0);
                        }
                    }
                } else {
                    const int half = p >> 1;
                    if ((p & 1) == 0) {  // x path (f32->f16), K-half
                        const float* xp = x + ((size_t)bb * 512 + t) * 512 + half * 256 + l4 * 8;
                        #pragma unroll
                        for (int ks = 0; ks < 8; ++ks) {
                            const float4 p0 = *(const float4*)(xp + ks * 32);
                            const float4 p1 = *(const float4*)(xp + ks * 32 + 4);
                            f16x8 v = { (f16)p0.x,(f16)p0.y,(f16)p0.z,(f16)p0.w,
                                        (f16)p1.x,(f16)p1.y,(f16)p1.z,(f16)p1.w };
                            #pragma unroll
                            for (int nf = 0; nf < 4; ++nf) {
                                f16x8 w = *(const f16x8*)(lds + (size_t)((half * 8 + ks) * 4 + nf) * 1024
                                                          + lane * 16);
                                acc[nf] = __builtin_amdgcn_mfma_f32_16x16x32_f16(w, v, acc[nf], 0, 0, 0);
                            }
                        }
                    } else {             // hh path, K-half
                        ldblob8((const char*)hprev + bb * 1024 + half * 512 + l4 * 16, hv);
                        waitvm0();
                        #pragma unroll
                        for (int ks = 0; ks < 8; ++ks) {
                            #pragma unroll
                            for (int nf = 0; nf < 4; ++nf) {
                                f16x8 w = *(const f16x8*)(lds + (size_t)(64 + (half * 8 + ks) * 4 + nf) * 1024
                                                          + lane * 16);
                                acc[nf] = __builtin_amdgcn_mfma_f32_16x16x32_f16(w, hv[ks], acc[nf], 0, 0, 0);
                            }
                        }
                    }
                }
            } else {
                const int s = step;
                const int kh = p & 1, kq = p >> 1;
                const f16* src = (kh == 0) ? (h0 + (size_t)(s & 3) * 65536)        // ih: h0(s)
                                           : (h1 + (size_t)((s - 1) & 1) * 65536); // hh: h1(s-1)
                ldblob8((const char*)src + bb * 1024 + kq * 512 + l4 * 16, hv);
                waitvm0();
                #pragma unroll
                for (int ks = 0; ks < 8; ++ks) {
                    #pragma unroll
                    for (int nf = 0; nf < 4; ++nf) {
                        f16x8 w = *(const f16x8*)(lds + (size_t)(kh * 64 + (kq * 8 + ks) * 4 + nf) * 1024
                                                  + lane * 16);
                        acc[nf] = __builtin_amdgcn_mfma_f32_16x16x32_f16(w, hv[ks], acc[nf], 0, 0, 0);
                    }
                }
            }

            if (p != 0) {
                #pragma unroll
                for (int nf = 0; nf < 4; ++nf)
                    *(f32x4*)(Rbuf + ((((p - 1) * 2 + mfg) * 4 + nf) * 64 + lane) * 16) = acc[nf];
            }
        }
        __syncthreads();                   // Rbuf visible

        if (active && p == 0) {
            #pragma unroll
            for (int q = 0; q < 3; ++q)
                #pragma unroll
                for (int nf = 0; nf < 4; ++nf)
                    acc[nf] += *(const f32x4*)(Rbuf + (((q * 2 + mfg) * 4 + nf) * 64 + lane) * 16);

            const bool msk = step < lb;
            #pragma unroll
            for (int nf = 0; nf < 4; ++nf) {
                float g0, g1, g2, g3;
                if (layer == 0 && pre) {
                    g0 = (float)x0v[nf][0]; g1 = (float)x0v[nf][1];
                    g2 = (float)x0v[nf][2]; g3 = (float)x0v[nf][3];
                } else {
                    g0 = bias4[nf].x; g1 = bias4[nf].y; g2 = bias4[nf].z; g3 = bias4[nf].w;
                }
                const float gi = acc[nf][0] + g0, gf = acc[nf][1] + g1;
                const float gg = acc[nf][2] + g2, go = acc[nf][3] + g3;
                const float cn = (1.f / (1.f + expf(-gf))) * c_s[nf]
                               + (1.f / (1.f + expf(-gi))) * tanhf(gg);
                const float hn = (1.f / (1.f + expf(-go))) * tanhf(cn);
                if (msk) { c_s[nf] = cn; h_s[nf] = (f16)hn; }
                *(f16*)(hstage + (mfg * 16 + l16) * 32 + (nf * 4 + l4) * 2) = h_s[nf];
                if (layer == 1 && step == lb - 1)
                    h1f[(size_t)bb * 512 + cg * 16 + nf * 4 + l4] = hn;
            }
        }
        __syncthreads();                   // hstage visible

        if (active && tid < 64) {          // 32 rows x thread-pair 32B stores (FIXED guard)
            f16* hw = (layer == 0) ? (h0 + (size_t)(t & 3) * 65536)
                                   : (h1 + (size_t)(step & 1) * 65536);
            const int bl = tid >> 1, half = tid & 1;
            f16x8 v = *(const f16x8*)(hstage + bl * 32 + half * 16);
            stwt16((char*)hw + (size_t)(bg * 32 + bl) * 1024 + cg * 32 + half * 16, v);
        }

        __syncthreads();                   // drains h stores before publishing
        if (tid == 0)
            __hip_atomic_store(bar + (layer * 4 + bg) * 128 + cg * 4, t + 1,
                               __ATOMIC_RELAXED, __HIP_MEMORY_SCOPE_AGENT);
    }
}

// ---------------- final FC ----------------
__global__ __launch_bounds__(256) void k_fc(const float* __restrict__ h1f,
                                            const float* __restrict__ wfc,
                                            const float* __restrict__ bfc,
                                            float* __restrict__ out) {
    int b = blockIdx.x;
    float s0 = 0, s1 = 0, s2 = 0, s3 = 0;
    for (int h = threadIdx.x; h < 512; h += 256) {
        float v = h1f[(size_t)b * 512 + h];
        s0 += v * wfc[h];
        s1 += v * wfc[512 + h];
        s2 += v * wfc[1024 + h];
        s3 += v * wfc[1536 + h];
    }
    #pragma unroll
    for (int off = 32; off; off >>= 1) {
        s0 += __shfl_down(s0, off);
        s1 += __shfl_down(s1, off);
        s2 += __shfl_down(s2, off);
        s3 += __shfl_down(s3, off);
    }
    __shared__ float red[4][4];
    int wid = threadIdx.x >> 6;
    if ((threadIdx.x & 63) == 0) { red[wid][0] = s0; red[wid][1] = s1; red[wid][2] = s2; red[wid][3] = s3; }
    __syncthreads();
    if (threadIdx.x < 4) {
        float s = red[0][threadIdx.x] + red[1][threadIdx.x] + red[2][threadIdx.x] + red[3][threadIdx.x]
                + bfc[threadIdx.x];
        out[b * 4 + threadIdx.x] = s;
    }
}

extern "C" void kernel_launch(void* const* d_in, const int* in_sizes, int n_in,
                              void* d_out, int out_size, void* d_ws, size_t ws_size,
                              hipStream_t stream) {
    const float* x    = (const float*)d_in[0];
    const float* wih0 = (const float*)d_in[1];
    const float* whh0 = (const float*)d_in[2];
    const float* bih0 = (const float*)d_in[3];
    const float* bhh0 = (const float*)d_in[4];
    const float* wih1 = (const float*)d_in[5];
    const float* whh1 = (const float*)d_in[6];
    const float* bih1 = (const float*)d_in[7];
    const float* bhh1 = (const float*)d_in[8];
    const float* wfc  = (const float*)d_in[9];
    const float* bfc  = (const float*)d_in[10];

    if (ws_size < WS_BASE) return;
    const int pre = (ws_size >= WS_PRE) ? 1 : 0;

    char* ws = (char*)d_ws;
    int*   bar   = (int*)(ws + OFF_BAR);
    int*   len   = (int*)(ws + OFF_LEN);
    float* bias0 = (float*)(ws + OFF_BIAS0);
    float* bias1 = (float*)(ws + OFF_BIAS1);
    f16*   W0    = (f16*)(ws + OFF_W0);
    f16*   W1    = (f16*)(ws + OFF_W1);
    f16*   h0    = (f16*)(ws + OFF_H0);
    f16*   h1    = (f16*)(ws + OFF_H1);
    float* h1f   = (float*)(ws + OFF_H1F);
    f16*   X0p   = (f16*)(ws + OFF_X0);

    hipMemsetAsync(ws, 0, 8192, stream);                        // barrier slots + len
    hipMemsetAsync(ws + OFF_H0, 0, WS_BASE - OFF_H0, stream);   // h state + h1f

    k_len<<<dim3(B_, 4), 512, 0, stream>>>(x, len);
    k_wcvt<<<2048, 256, 0, stream>>>(wih0, whh0, bih0, bhh0, W0, bias0);
    k_wcvt<<<2048, 256, 0, stream>>>(wih1, whh1, bih1, bhh1, W1, bias1);
    if (pre) {
        hipFuncSetAttribute((const void*)k_xgemm, hipFuncAttributeMaxDynamicSharedMemorySize, 139264);
        k_xgemm<<<dim3(128, 8), 256, 139264, stream>>>(x, W0, bias0, X0p);
    }

    hipFuncSetAttribute((const void*)k_persist, hipFuncAttributeMaxDynamicSharedMemorySize, 156672);
    const f16* X0c = X0p;
    void* kargs[] = {
        (void*)&x, (void*)&W0, (void*)&W1, (void*)&bias0, (void*)&bias1, (void*)&len,
        (void*)&h0, (void*)&h1, (void*)&h1f,
        (void*)&X0c, (void*)&pre, (void*)&bar
    };
    hipLaunchCooperativeKernel((const void*)k_persist, dim3(NBLK), dim3(512),
                               kargs, 156672, stream);

    k_fc<<<B_, 256, 0, stream>>>(h1f, wfc, bfc, (float*)d_out);
}